// Round 6
// baseline (335.089 us; speedup 1.0000x reference)
//
#include <hip/hip_runtime.h>
#include <stdint.h>

#define CHN 512
#define TDIM 4096
#define SD 256
#define HD 128
#define NTOK 50
#define NP 64
#define NB 16
#define TT 64        // t-rows per block
#define QPITCH 264   // elems; row stride 528 B (16B aligned)
#define XPITCH 132   // elems; row stride 264 B (8B aligned)
#define SCALE_ 0.0625f

typedef float f32x4 __attribute__((ext_vector_type(4)));
typedef unsigned int u32x4 __attribute__((ext_vector_type(4)));
typedef short s16x8 __attribute__((ext_vector_type(8)));

__device__ __forceinline__ uint16_t f2bf(float f) {
  union { float f; uint32_t u; } v; v.f = f;
  uint32_t r = (v.u + 0x7fffu + ((v.u >> 16) & 1u)) >> 16;
  return (uint16_t)r;
}
__device__ __forceinline__ uint32_t packbf(float lo, float hi) {
  return (uint32_t)f2bf(lo) | ((uint32_t)f2bf(hi) << 16);
}
__device__ __forceinline__ void mfma_bf16(f32x4& d, u32x4 a, u32x4 b) {
  union { u32x4 u; s16x8 s; } ua, ub;
  ua.u = a; ub.u = b;
  d = __builtin_amdgcn_mfma_f32_16x16x32_bf16(ua.s, ub.s, d, 0, 0, 0);
}

// ---------------- prep kernels ----------------
__global__ void conv_w_kernel(const float* __restrict__ Wq, const float* __restrict__ Wo,
                              uint16_t* __restrict__ wqb, uint16_t* __restrict__ wob) {
  int i = blockIdx.x * 256 + threadIdx.x;   // 131072 each
  wqb[i] = f2bf(Wq[i]);
  wob[i] = f2bf(Wo[i]);
}

__global__ void prep_kv_kernel(const float* __restrict__ style, const float* __restrict__ kemb,
                               const float* __restrict__ Wk, const float* __restrict__ bk,
                               const float* __restrict__ Wv, const float* __restrict__ bv,
                               uint16_t* __restrict__ kt, uint16_t* __restrict__ vT) {
  int id = blockIdx.x * 256 + threadIdx.x;
  if (id < 2 * NP * HD) {                    // kt[h][n][dh], tanh applied
    int dh = id & (HD - 1);
    int n  = (id >> 7) & (NP - 1);
    int h  = id >> 13;
    uint16_t r = 0;
    if (n < NTOK) {
      int d = h * HD + dh;
      float acc = bk[d];
      const float* er = kemb + (size_t)n * SD;
      const float* wr = Wk + (size_t)d * SD;
      for (int s = 0; s < SD; s += 4) {
        float4 e = *(const float4*)(er + s);
        float4 w4 = *(const float4*)(wr + s);
        acc += e.x * w4.x + e.y * w4.y + e.z * w4.z + e.w * w4.w;
      }
      r = f2bf(tanhf(acc));
    }
    kt[id] = r;
  } else {                                   // vT[b][h][dh][n]
    int vid = id - 2 * NP * HD;
    int n  = vid & (NP - 1);
    int dh = (vid >> 6) & (HD - 1);
    int h  = (vid >> 13) & 1;
    int bb = vid >> 14;
    uint16_t r = 0;
    if (n < NTOK) {
      int d = h * HD + dh;
      float acc = bv[d];
      const float* sr = style + (size_t)(bb * NTOK + n) * SD;
      const float* wr = Wv + (size_t)d * SD;
      for (int s = 0; s < SD; s += 4) {
        float4 e = *(const float4*)(sr + s);
        float4 w4 = *(const float4*)(wr + s);
        acc += e.x * w4.x + e.y * w4.y + e.z * w4.z + e.w * w4.w;
      }
      r = f2bf(acc);
    }
    vT[vid] = r;
  }
}

// ---------------- fused main kernel ----------------
// 256 threads = 4 waves; block does 64 t-rows. LDS 33.8 KB -> 4 blocks/CU.
__global__ __launch_bounds__(256, 4) void fused_kernel(
    const float* __restrict__ x, const float* __restrict__ bq, const float* __restrict__ bo,
    const uint16_t* __restrict__ wqb, const uint16_t* __restrict__ wob,
    const uint16_t* __restrict__ kt, const uint16_t* __restrict__ vT,
    float* __restrict__ out) {
  __shared__ uint16_t qs[TT * QPITCH];   // 33,792 B; x-tile staging aliases front

  const int bb = blockIdx.y;
  const int t0 = blockIdx.x * TT;
  const int tid = threadIdx.x;
  const int lane = tid & 63;
  const int w = tid >> 6;        // 0..3
  const int l15 = lane & 15;
  const int g = lane >> 4;       // 0..3

  const float* xb = x + (size_t)bb * CHN * TDIM + t0;

  // ---- phase 1: q[d][t] = Wq * x_tile  (K = 512, 4 chunks of 128 c) ----
  // wave w owns d-quadrant [64w, 64w+64), all 64 t.
  f32x4 acc[4][4];
#pragma unroll
  for (int mt = 0; mt < 4; ++mt)
#pragma unroll
    for (int nt = 0; nt < 4; ++nt) acc[mt][nt] = (f32x4){0.f, 0.f, 0.f, 0.f};

  // staging: thread covers t = tse, tse+1 for rows c = cb, cb+1 (+16p)
  const int tse = (tid & 31) << 1;   // 0..62
  const int cb  = (tid >> 5) << 1;   // 0,2,..,14

  float2 va[8], vb[8];
#pragma unroll
  for (int p = 0; p < 8; ++p) {      // prefetch chunk 0
    int c = cb + 16 * p;
    va[p] = *(const float2*)(xb + (size_t)c * TDIM + tse);
    vb[p] = *(const float2*)(xb + (size_t)(c + 1) * TDIM + tse);
  }

  for (int cc = 0; cc < 4; ++cc) {
    const int c0 = cc * 128;
    __syncthreads();   // prev chunk's LDS reads complete (no-op for cc=0)
#pragma unroll
    for (int p = 0; p < 8; ++p) {
      int cl = cb + 16 * p;
      *(uint32_t*)&qs[tse * XPITCH + cl]       = packbf(va[p].x, vb[p].x);
      *(uint32_t*)&qs[(tse + 1) * XPITCH + cl] = packbf(va[p].y, vb[p].y);
    }
    if (cc < 3) {                    // issue next chunk's loads early
      const int c0n = c0 + 128;
#pragma unroll
      for (int p = 0; p < 8; ++p) {
        int c = c0n + cb + 16 * p;
        va[p] = *(const float2*)(xb + (size_t)c * TDIM + tse);
        vb[p] = *(const float2*)(xb + (size_t)(c + 1) * TDIM + tse);
      }
    }
    __syncthreads();
#pragma unroll
    for (int ks = 0; ks < 4; ++ks) {
      u32x4 afr[4];
#pragma unroll
      for (int mt = 0; mt < 4; ++mt) {
        int dr = (w * 4 + mt) * 16 + l15;
        afr[mt] = *(const u32x4*)(wqb + (size_t)dr * CHN + c0 + ks * 32 + g * 8);
      }
#pragma unroll
      for (int nt = 0; nt < 4; ++nt) {
        int tr = nt * 16 + l15;
        const uint16_t* pb = &qs[tr * XPITCH + ks * 32 + g * 8];
        uint2 lo = *(const uint2*)pb;
        uint2 hi = *(const uint2*)(pb + 4);
        u32x4 bfr = (u32x4){lo.x, lo.y, hi.x, hi.y};
#pragma unroll
        for (int mt = 0; mt < 4; ++mt) mfma_bf16(acc[mt][nt], afr[mt], bfr);
      }
    }
  }
  __syncthreads();
  // write q + bq to qs[t][d]  (D-frag: col t = l15, rows d = g*4+j)
#pragma unroll
  for (int mt = 0; mt < 4; ++mt) {
    int d0 = (w * 4 + mt) * 16 + g * 4;
    float4 bqv = *(const float4*)(bq + d0);
#pragma unroll
    for (int nt = 0; nt < 4; ++nt) {
      int tr = nt * 16 + l15;
      uint2 wv;
      wv.x = packbf(acc[mt][nt][0] + bqv.x, acc[mt][nt][1] + bqv.y);
      wv.y = packbf(acc[mt][nt][2] + bqv.z, acc[mt][nt][3] + bqv.w);
      *(uint2*)&qs[tr * QPITCH + d0] = wv;
    }
  }
  __syncthreads();   // last barrier: rest is wave-private rows

  // ---- phases 2-3 per head: s^T = kt*q^T -> softmax -> o^T = vT*p^T ----
  const int tmy = w * 16 + l15;     // 0..63
  const uint16_t* qrow = &qs[tmy * QPITCH];
  const int l1 = l15 + 16 * ((2 * g) & 3);
  const int l2 = l15 + 16 * ((2 * g + 1) & 3);
  const bool hiH = (g >> 1) != 0;

#pragma unroll
  for (int h = 0; h < 2; ++h) {
    u32x4 bq4[4];
#pragma unroll
    for (int ks = 0; ks < 4; ++ks)
      bq4[ks] = *(const u32x4*)(qrow + h * HD + ks * 32 + g * 8);

    f32x4 sac[4];
#pragma unroll
    for (int mtn = 0; mtn < 4; ++mtn) {
      sac[mtn] = (f32x4){0.f, 0.f, 0.f, 0.f};
#pragma unroll
      for (int ks = 0; ks < 4; ++ks) {
        u32x4 afr = *(const u32x4*)(kt + (size_t)(h * NP + mtn * 16 + l15) * HD + ks * 32 + g * 8);
        mfma_bf16(sac[mtn], afr, bq4[ks]);
      }
    }
    // softmax over n (64 padded)
    float pv[4][4];
    float mx = -3.0e38f;
#pragma unroll
    for (int mtn = 0; mtn < 4; ++mtn)
#pragma unroll
      for (int j = 0; j < 4; ++j) {
        int n = mtn * 16 + g * 4 + j;
        float s = (n < NTOK) ? sac[mtn][j] * SCALE_ : -3.0e38f;
        pv[mtn][j] = s;
        mx = fmaxf(mx, s);
      }
    mx = fmaxf(mx, __shfl_xor(mx, 16, 64));
    mx = fmaxf(mx, __shfl_xor(mx, 32, 64));
    float sum = 0.f;
#pragma unroll
    for (int mtn = 0; mtn < 4; ++mtn)
#pragma unroll
      for (int j = 0; j < 4; ++j) {
        float e = __expf(pv[mtn][j] - mx);
        pv[mtn][j] = e;
        sum += e;
      }
    sum += __shfl_xor(sum, 16, 64);
    sum += __shfl_xor(sum, 32, 64);
    float inv = 1.0f / sum;
    uint32_t pk[4][2];
#pragma unroll
    for (int mtn = 0; mtn < 4; ++mtn) {
      pk[mtn][0] = packbf(pv[mtn][0] * inv, pv[mtn][1] * inv);
      pk[mtn][1] = packbf(pv[mtn][2] * inv, pv[mtn][3] * inv);
    }
    // redistribute P: D-frag -> B-frag via shuffles
    u32x4 bp[2];
#pragma unroll
    for (int ks = 0; ks < 2; ++ks) {
      uint32_t a0 = (uint32_t)__shfl((int)pk[2 * ks][0], l1, 64);
      uint32_t b0 = (uint32_t)__shfl((int)pk[2 * ks + 1][0], l1, 64);
      uint32_t a1 = (uint32_t)__shfl((int)pk[2 * ks][1], l1, 64);
      uint32_t b1 = (uint32_t)__shfl((int)pk[2 * ks + 1][1], l1, 64);
      uint32_t a2 = (uint32_t)__shfl((int)pk[2 * ks][0], l2, 64);
      uint32_t b2 = (uint32_t)__shfl((int)pk[2 * ks + 1][0], l2, 64);
      uint32_t a3 = (uint32_t)__shfl((int)pk[2 * ks][1], l2, 64);
      uint32_t b3 = (uint32_t)__shfl((int)pk[2 * ks + 1][1], l2, 64);
      bp[ks] = (u32x4){hiH ? b0 : a0, hiH ? b1 : a1, hiH ? b2 : a2, hiH ? b3 : a3};
    }
    // o^T[d][t] = vT * p^T ; overwrite q's columns of this head (dead now)
    const uint16_t* vb2 = vT + (size_t)((bb * 2 + h) * HD) * NP;
#pragma unroll
    for (int mtd = 0; mtd < 8; ++mtd) {
      f32x4 oac = (f32x4){0.f, 0.f, 0.f, 0.f};
#pragma unroll
      for (int ks = 0; ks < 2; ++ks) {
        u32x4 afr = *(const u32x4*)(vb2 + (size_t)(mtd * 16 + l15) * NP + ks * 32 + g * 8);
        mfma_bf16(oac, afr, bp[ks]);
      }
      int d0 = h * HD + mtd * 16 + g * 4;
      uint2 wv;
      wv.x = packbf(oac[0], oac[1]);
      wv.y = packbf(oac[2], oac[3]);
      *(uint2*)&qs[tmy * QPITCH + d0] = wv;
    }
  }

  // ---- phase 4: y[t][c] = o * Wo^T ; out = x + y (+bo) ----
  u32x4 ak[8];
#pragma unroll
  for (int ks = 0; ks < 8; ++ks)
    ak[ks] = *(const u32x4*)(qrow + ks * 32 + g * 8);

  const float* xr = x + (size_t)bb * CHN * TDIM;
  float* orow = out + (size_t)bb * CHN * TDIM;
  const int t4 = t0 + w * 16 + g * 4;

  float4 xg[8];
#pragma unroll
  for (int i = 0; i < 8; ++i) {
    int c = i * 16 + l15;
    xg[i] = *(const float4*)(xr + (size_t)c * TDIM + t4);
  }
#pragma unroll
  for (int nt = 0; nt < 32; ++nt) {
    int c = nt * 16 + l15;
    const uint16_t* wrow = wob + (size_t)c * SD;
    f32x4 yac = (f32x4){0.f, 0.f, 0.f, 0.f};
#pragma unroll
    for (int ks = 0; ks < 8; ++ks) {
      u32x4 bfr = *(const u32x4*)(wrow + ks * 32 + g * 8);
      mfma_bf16(yac, ak[ks], bfr);
    }
    float bov = bo[c];
    float4 xv = xg[nt & 7];
    if (nt + 8 < 32) {
      int c2 = (nt + 8) * 16 + l15;
      xg[nt & 7] = *(const float4*)(xr + (size_t)c2 * TDIM + t4);
    }
    float4 ov;
    ov.x = xv.x + yac[0] + bov;
    ov.y = xv.y + yac[1] + bov;
    ov.z = xv.z + yac[2] + bov;
    ov.w = xv.w + yac[3] + bov;
    *(float4*)(orow + (size_t)c * TDIM + t4) = ov;
  }
}

extern "C" void kernel_launch(void* const* d_in, const int* in_sizes, int n_in,
                              void* d_out, int out_size, void* d_ws, size_t ws_size,
                              hipStream_t stream) {
  const float* x     = (const float*)d_in[0];
  const float* style = (const float*)d_in[1];
  const float* kemb  = (const float*)d_in[2];
  const float* Wq    = (const float*)d_in[3];
  const float* bq    = (const float*)d_in[4];
  const float* Wk    = (const float*)d_in[5];
  const float* bk    = (const float*)d_in[6];
  const float* Wv    = (const float*)d_in[7];
  const float* bv    = (const float*)d_in[8];
  const float* Wo    = (const float*)d_in[9];
  const float* bo    = (const float*)d_in[10];
  float* out = (float*)d_out;

  uint16_t* wqb = (uint16_t*)d_ws;        // 131072 elems (Wq bf16, [d][c])
  uint16_t* wob = wqb + 131072;           // 131072 (Wo bf16, [c][d])
  uint16_t* ktw = wob + 131072;           // 16384  (tanh(K), [h][n(64)][d])
  uint16_t* vTw = ktw + 16384;            // 262144 (V^T, [b][h][d][n(64)])
  // total ws use: 1,081,344 bytes

  conv_w_kernel<<<512, 256, 0, stream>>>(Wq, Wo, wqb, wob);
  prep_kv_kernel<<<1088, 256, 0, stream>>>(style, kemb, Wk, bk, Wv, bv, ktw, vTw);
  dim3 grid(TDIM / TT, NB);
  fused_kernel<<<grid, 256, 0, stream>>>(x, bq, bo, wqb, wob, ktw, vTw, out);
}

// Round 7
// 253.242 us; speedup vs baseline: 1.3232x; 1.3232x over previous
//
#include <hip/hip_runtime.h>
#include <stdint.h>

#define CHN 512
#define TDIM 4096
#define SD 256
#define HD 128
#define NTOK 50
#define NP 64
#define NB 16
#define TT 64        // t-rows per block
#define QPITCH 264   // elems; row stride 528 B (16B aligned)
#define XPITCH 132   // elems; row stride 264 B (8B aligned)
#define SCALE_ 0.0625f

typedef float f32x4 __attribute__((ext_vector_type(4)));
typedef unsigned int u32x4 __attribute__((ext_vector_type(4)));
typedef short s16x8 __attribute__((ext_vector_type(8)));

__device__ __forceinline__ uint16_t f2bf(float f) {
  union { float f; uint32_t u; } v; v.f = f;
  uint32_t r = (v.u + 0x7fffu + ((v.u >> 16) & 1u)) >> 16;
  return (uint16_t)r;
}
__device__ __forceinline__ uint32_t packbf(float lo, float hi) {
  return (uint32_t)f2bf(lo) | ((uint32_t)f2bf(hi) << 16);
}
__device__ __forceinline__ void mfma_bf16(f32x4& d, u32x4 a, u32x4 b) {
  union { u32x4 u; s16x8 s; } ua, ub;
  ua.u = a; ub.u = b;
  d = __builtin_amdgcn_mfma_f32_16x16x32_bf16(ua.s, ub.s, d, 0, 0, 0);
}

// ---------------- prep kernels ----------------
__global__ void conv_w_kernel(const float* __restrict__ Wq, const float* __restrict__ Wo,
                              uint16_t* __restrict__ wqb, uint16_t* __restrict__ wob) {
  int i = blockIdx.x * 256 + threadIdx.x;   // 131072 each
  wqb[i] = f2bf(Wq[i]);
  wob[i] = f2bf(Wo[i]);
}

__global__ void prep_kv_kernel(const float* __restrict__ style, const float* __restrict__ kemb,
                               const float* __restrict__ Wk, const float* __restrict__ bk,
                               const float* __restrict__ Wv, const float* __restrict__ bv,
                               uint16_t* __restrict__ kt, uint16_t* __restrict__ vT) {
  int id = blockIdx.x * 256 + threadIdx.x;
  if (id < 2 * NP * HD) {                    // kt[h][n][dh], tanh applied
    int dh = id & (HD - 1);
    int n  = (id >> 7) & (NP - 1);
    int h  = id >> 13;
    uint16_t r = 0;
    if (n < NTOK) {
      int d = h * HD + dh;
      float acc = bk[d];
      const float* er = kemb + (size_t)n * SD;
      const float* wr = Wk + (size_t)d * SD;
      for (int s = 0; s < SD; s += 4) {
        float4 e = *(const float4*)(er + s);
        float4 w4 = *(const float4*)(wr + s);
        acc += e.x * w4.x + e.y * w4.y + e.z * w4.z + e.w * w4.w;
      }
      r = f2bf(tanhf(acc));
    }
    kt[id] = r;
  } else {                                   // vT[b][h][dh][n]
    int vid = id - 2 * NP * HD;
    int n  = vid & (NP - 1);
    int dh = (vid >> 6) & (HD - 1);
    int h  = (vid >> 13) & 1;
    int bb = vid >> 14;
    uint16_t r = 0;
    if (n < NTOK) {
      int d = h * HD + dh;
      float acc = bv[d];
      const float* sr = style + (size_t)(bb * NTOK + n) * SD;
      const float* wr = Wv + (size_t)d * SD;
      for (int s = 0; s < SD; s += 4) {
        float4 e = *(const float4*)(sr + s);
        float4 w4 = *(const float4*)(wr + s);
        acc += e.x * w4.x + e.y * w4.y + e.z * w4.z + e.w * w4.w;
      }
      r = f2bf(acc);
    }
    vT[vid] = r;
  }
}

// ---------------- fused main kernel ----------------
// 256 threads = 4 waves; block does 64 t-rows. LDS 33.8 KB -> 4 blocks/CU.
// launch_bounds arg2=2: empirically VGPR cap ~128 (arg2=4 capped at 64 -> spills).
__global__ __launch_bounds__(256, 2) void fused_kernel(
    const float* __restrict__ x, const float* __restrict__ bq, const float* __restrict__ bo,
    const uint16_t* __restrict__ wqb, const uint16_t* __restrict__ wob,
    const uint16_t* __restrict__ kt, const uint16_t* __restrict__ vT,
    float* __restrict__ out) {
  __shared__ uint16_t qs[TT * QPITCH];   // 33,792 B; x-tile staging aliases front

  const int bb = blockIdx.y;
  const int t0 = blockIdx.x * TT;
  const int tid = threadIdx.x;
  const int lane = tid & 63;
  const int w = tid >> 6;        // 0..3
  const int l15 = lane & 15;
  const int g = lane >> 4;       // 0..3

  const float* xb = x + (size_t)bb * CHN * TDIM + t0;

  // ---- phase 1: q[d][t] = Wq * x_tile  (K = 512, 4 chunks of 128 c) ----
  // wave w owns d-quadrant [64w, 64w+64), all 64 t.
  f32x4 acc[4][4];
#pragma unroll
  for (int mt = 0; mt < 4; ++mt)
#pragma unroll
    for (int nt = 0; nt < 4; ++nt) acc[mt][nt] = (f32x4){0.f, 0.f, 0.f, 0.f};

  // staging: thread covers t = tse, tse+1 for rows c = cb, cb+1 (+16p)
  const int tse = (tid & 31) << 1;   // 0..62
  const int cb  = (tid >> 5) << 1;   // 0,2,..,14

  float2 va[8], vb[8];
#pragma unroll
  for (int p = 0; p < 8; ++p) {      // prefetch chunk 0
    int c = cb + 16 * p;
    va[p] = *(const float2*)(xb + (size_t)c * TDIM + tse);
    vb[p] = *(const float2*)(xb + (size_t)(c + 1) * TDIM + tse);
  }

  for (int cc = 0; cc < 4; ++cc) {
    const int c0 = cc * 128;
    __syncthreads();   // prev chunk's LDS reads complete (no-op for cc=0)
#pragma unroll
    for (int p = 0; p < 8; ++p) {
      int cl = cb + 16 * p;
      *(uint32_t*)&qs[tse * XPITCH + cl]       = packbf(va[p].x, vb[p].x);
      *(uint32_t*)&qs[(tse + 1) * XPITCH + cl] = packbf(va[p].y, vb[p].y);
    }
    if (cc < 3) {                    // issue next chunk's loads early
      const int c0n = c0 + 128;
#pragma unroll
      for (int p = 0; p < 8; ++p) {
        int c = c0n + cb + 16 * p;
        va[p] = *(const float2*)(xb + (size_t)c * TDIM + tse);
        vb[p] = *(const float2*)(xb + (size_t)(c + 1) * TDIM + tse);
      }
    }
    __syncthreads();
#pragma unroll
    for (int ks = 0; ks < 4; ++ks) {
      u32x4 afr[4];
#pragma unroll
      for (int mt = 0; mt < 4; ++mt) {
        int dr = (w * 4 + mt) * 16 + l15;
        afr[mt] = *(const u32x4*)(wqb + (size_t)dr * CHN + c0 + ks * 32 + g * 8);
      }
#pragma unroll
      for (int nt = 0; nt < 4; ++nt) {
        int tr = nt * 16 + l15;
        const uint16_t* pb = &qs[tr * XPITCH + ks * 32 + g * 8];
        uint2 lo = *(const uint2*)pb;
        uint2 hi = *(const uint2*)(pb + 4);
        u32x4 bfr = (u32x4){lo.x, lo.y, hi.x, hi.y};
#pragma unroll
        for (int mt = 0; mt < 4; ++mt) mfma_bf16(acc[mt][nt], afr[mt], bfr);
      }
    }
  }
  __syncthreads();
  // write q + bq to qs[t][d]  (D-frag: col t = l15, rows d = g*4+j)
#pragma unroll
  for (int mt = 0; mt < 4; ++mt) {
    int d0 = (w * 4 + mt) * 16 + g * 4;
    float4 bqv = *(const float4*)(bq + d0);
#pragma unroll
    for (int nt = 0; nt < 4; ++nt) {
      int tr = nt * 16 + l15;
      uint2 wv;
      wv.x = packbf(acc[mt][nt][0] + bqv.x, acc[mt][nt][1] + bqv.y);
      wv.y = packbf(acc[mt][nt][2] + bqv.z, acc[mt][nt][3] + bqv.w);
      *(uint2*)&qs[tr * QPITCH + d0] = wv;
    }
  }
  __syncthreads();   // last barrier: rest is wave-private rows

  // ---- phases 2-3 per head: s^T = kt*q^T -> softmax -> o^T = vT*p^T ----
  const int tmy = w * 16 + l15;     // 0..63
  const uint16_t* qrow = &qs[tmy * QPITCH];
  const int l1 = l15 + 16 * ((2 * g) & 3);
  const int l2 = l15 + 16 * ((2 * g + 1) & 3);
  const bool hiH = (g >> 1) != 0;

#pragma unroll
  for (int h = 0; h < 2; ++h) {
    u32x4 bq4[4];
#pragma unroll
    for (int ks = 0; ks < 4; ++ks)
      bq4[ks] = *(const u32x4*)(qrow + h * HD + ks * 32 + g * 8);

    f32x4 sac[4];
#pragma unroll
    for (int mtn = 0; mtn < 4; ++mtn) {
      sac[mtn] = (f32x4){0.f, 0.f, 0.f, 0.f};
#pragma unroll
      for (int ks = 0; ks < 4; ++ks) {
        u32x4 afr = *(const u32x4*)(kt + (size_t)(h * NP + mtn * 16 + l15) * HD + ks * 32 + g * 8);
        mfma_bf16(sac[mtn], afr, bq4[ks]);
      }
    }
    // softmax over n (64 padded)
    float pv[4][4];
    float mx = -3.0e38f;
#pragma unroll
    for (int mtn = 0; mtn < 4; ++mtn)
#pragma unroll
      for (int j = 0; j < 4; ++j) {
        int n = mtn * 16 + g * 4 + j;
        float s = (n < NTOK) ? sac[mtn][j] * SCALE_ : -3.0e38f;
        pv[mtn][j] = s;
        mx = fmaxf(mx, s);
      }
    mx = fmaxf(mx, __shfl_xor(mx, 16, 64));
    mx = fmaxf(mx, __shfl_xor(mx, 32, 64));
    float sum = 0.f;
#pragma unroll
    for (int mtn = 0; mtn < 4; ++mtn)
#pragma unroll
      for (int j = 0; j < 4; ++j) {
        float e = __expf(pv[mtn][j] - mx);
        pv[mtn][j] = e;
        sum += e;
      }
    sum += __shfl_xor(sum, 16, 64);
    sum += __shfl_xor(sum, 32, 64);
    float inv = 1.0f / sum;
    uint32_t pk[4][2];
#pragma unroll
    for (int mtn = 0; mtn < 4; ++mtn) {
      pk[mtn][0] = packbf(pv[mtn][0] * inv, pv[mtn][1] * inv);
      pk[mtn][1] = packbf(pv[mtn][2] * inv, pv[mtn][3] * inv);
    }
    // redistribute P: D-frag -> B-frag via shuffles
    u32x4 bp[2];
#pragma unroll
    for (int ks = 0; ks < 2; ++ks) {
      uint32_t a0 = (uint32_t)__shfl((int)pk[2 * ks][0], l1, 64);
      uint32_t b0 = (uint32_t)__shfl((int)pk[2 * ks + 1][0], l1, 64);
      uint32_t a1 = (uint32_t)__shfl((int)pk[2 * ks][1], l1, 64);
      uint32_t b1 = (uint32_t)__shfl((int)pk[2 * ks + 1][1], l1, 64);
      uint32_t a2 = (uint32_t)__shfl((int)pk[2 * ks][0], l2, 64);
      uint32_t b2 = (uint32_t)__shfl((int)pk[2 * ks + 1][0], l2, 64);
      uint32_t a3 = (uint32_t)__shfl((int)pk[2 * ks][1], l2, 64);
      uint32_t b3 = (uint32_t)__shfl((int)pk[2 * ks + 1][1], l2, 64);
      bp[ks] = (u32x4){hiH ? b0 : a0, hiH ? b1 : a1, hiH ? b2 : a2, hiH ? b3 : a3};
    }
    // o^T[d][t] = vT * p^T ; overwrite q's columns of this head (dead now)
    const uint16_t* vb2 = vT + (size_t)((bb * 2 + h) * HD) * NP;
#pragma unroll
    for (int mtd = 0; mtd < 8; ++mtd) {
      f32x4 oac = (f32x4){0.f, 0.f, 0.f, 0.f};
#pragma unroll
      for (int ks = 0; ks < 2; ++ks) {
        u32x4 afr = *(const u32x4*)(vb2 + (size_t)(mtd * 16 + l15) * NP + ks * 32 + g * 8);
        mfma_bf16(oac, afr, bp[ks]);
      }
      int d0 = h * HD + mtd * 16 + g * 4;
      uint2 wv;
      wv.x = packbf(oac[0], oac[1]);
      wv.y = packbf(oac[2], oac[3]);
      *(uint2*)&qs[tmy * QPITCH + d0] = wv;
    }
  }

  // ---- phase 4: y[t][c] = o * Wo^T ; out = x + y (+bo) ----
  u32x4 ak[8];
#pragma unroll
  for (int ks = 0; ks < 8; ++ks)
    ak[ks] = *(const u32x4*)(qrow + ks * 32 + g * 8);

  const float* xr = x + (size_t)bb * CHN * TDIM;
  float* orow = out + (size_t)bb * CHN * TDIM;
  const int t4 = t0 + w * 16 + g * 4;

  float4 xg[8];
#pragma unroll
  for (int i = 0; i < 8; ++i) {
    int c = i * 16 + l15;
    xg[i] = *(const float4*)(xr + (size_t)c * TDIM + t4);
  }
#pragma unroll
  for (int nt = 0; nt < 32; ++nt) {
    int c = nt * 16 + l15;
    const uint16_t* wrow = wob + (size_t)c * SD;
    f32x4 yac = (f32x4){0.f, 0.f, 0.f, 0.f};
#pragma unroll
    for (int ks = 0; ks < 8; ++ks) {
      u32x4 bfr = *(const u32x4*)(wrow + ks * 32 + g * 8);
      mfma_bf16(yac, ak[ks], bfr);
    }
    float bov = bo[c];
    float4 xv = xg[nt & 7];
    if (nt + 8 < 32) {
      int c2 = (nt + 8) * 16 + l15;
      xg[nt & 7] = *(const float4*)(xr + (size_t)c2 * TDIM + t4);
    }
    float4 ov;
    ov.x = xv.x + yac[0] + bov;
    ov.y = xv.y + yac[1] + bov;
    ov.z = xv.z + yac[2] + bov;
    ov.w = xv.w + yac[3] + bov;
    *(float4*)(orow + (size_t)c * TDIM + t4) = ov;
  }
}

extern "C" void kernel_launch(void* const* d_in, const int* in_sizes, int n_in,
                              void* d_out, int out_size, void* d_ws, size_t ws_size,
                              hipStream_t stream) {
  const float* x     = (const float*)d_in[0];
  const float* style = (const float*)d_in[1];
  const float* kemb  = (const float*)d_in[2];
  const float* Wq    = (const float*)d_in[3];
  const float* bq    = (const float*)d_in[4];
  const float* Wk    = (const float*)d_in[5];
  const float* bk    = (const float*)d_in[6];
  const float* Wv    = (const float*)d_in[7];
  const float* bv    = (const float*)d_in[8];
  const float* Wo    = (const float*)d_in[9];
  const float* bo    = (const float*)d_in[10];
  float* out = (float*)d_out;

  uint16_t* wqb = (uint16_t*)d_ws;        // 131072 elems (Wq bf16, [d][c])
  uint16_t* wob = wqb + 131072;           // 131072 (Wo bf16, [c][d])
  uint16_t* ktw = wob + 131072;           // 16384  (tanh(K), [h][n(64)][d])
  uint16_t* vTw = ktw + 16384;            // 262144 (V^T, [b][h][d][n(64)])
  // total ws use: 1,081,344 bytes

  conv_w_kernel<<<512, 256, 0, stream>>>(Wq, Wo, wqb, wob);
  prep_kv_kernel<<<1088, 256, 0, stream>>>(style, kemb, Wk, bk, Wv, bv, ktw, vTw);
  dim3 grid(TDIM / TT, NB);
  fused_kernel<<<grid, 256, 0, stream>>>(x, bq, bo, wqb, wob, ktw, vTw, out);
}